// Round 9
// baseline (101.622 us; speedup 1.0000x reference)
//
#include <hip/hip_runtime.h>
#include <hip/hip_bf16.h>

// FMICLLoss: out = -mean(s_pos) + ALPHA * ( sum_{i!=j} exp(-d2_ij/2) / (N(N-1)) + EPS )
// N=8192, D=256, SIGMA=1 (inv2s2=0.5), ALPHA=1.5, EPS=1e-8, NORM_EPS=1e-12.
//
// Round 9 — DIAGNOSTIC: identical to R8 except the pair tile-loop runs TWICE
// (both passes accumulated, block partial * 0.5 at the end — exact). This
// pushes pair above the harness's ~43us fill dispatches so rocprof finally
// shows its counters (MfmaUtil / VALUBusy / LDS conflicts / FETCH_SIZE).
// Pair has been ~25us across 3 structural variants while the pipe model says
// ~9us; the counters decide between: staging-bound / LDS-conflict-bound /
// epilogue-VALU-bound / accounting-wrong (gaps dominate).
// Expected total ~105-112us (deliberate one-round regression for data).

#define N_ROWS 8192
#define DIM    256
#define LOG2E  1.4426950408889634f
#define NBLK   2080
#define GRID   512

typedef __attribute__((ext_vector_type(8))) int   int8v;
typedef __attribute__((ext_vector_type(4))) float f32x4;

#define GLDS16(gptr, lptr) \
  __builtin_amdgcn_global_load_lds((const __attribute__((address_space(1))) void*)(gptr), \
                                   (__attribute__((address_space(3))) void*)(lptr), 16, 0, 0)

__device__ inline void tri_decode(int t, int& bi, int& bj) {
    int u = NBLK - 1 - t;
    int k = (int)((sqrtf(8.0f * (float)u + 1.0f) - 1.0f) * 0.5f);
    while ((k + 1) * (k + 2) / 2 <= u) ++k;
    while (k * (k + 1) / 2 > u) --k;
    bi = 63 - k;
    bj = 63 - (u - k * (k + 1) / 2);
}

// ---------------------------------------------------------------------------
// Kernel 1: row-normalize z1,z2; write z1n8 (fp8 e4m3) + hl[i]=0.5*log2e*||z||^2;
// per-block s_pos partial. One wave per row. No atomics.
// ---------------------------------------------------------------------------
__global__ __launch_bounds__(256) void norm_kernel(
    const float* __restrict__ z1, const float* __restrict__ z2,
    unsigned char* __restrict__ z1n8, float* __restrict__ hl,
    float* __restrict__ spos_part) {

    int tid  = threadIdx.x;
    int wave = tid >> 6, lane = tid & 63;
    int row  = blockIdx.x * 4 + wave;

    const float4 a = *(const float4*)(z1 + (size_t)row * DIM + lane * 4);
    const float4 b = *(const float4*)(z2 + (size_t)row * DIM + lane * 4);

    float s1 = a.x*a.x + a.y*a.y + a.z*a.z + a.w*a.w;
    float s2 = b.x*b.x + b.y*b.y + b.z*b.z + b.w*b.w;
    #pragma unroll
    for (int off = 32; off; off >>= 1) {
        s1 += __shfl_xor(s1, off);
        s2 += __shfl_xor(s2, off);
    }
    float m1 = fmaxf(sqrtf(s1), 1e-12f);
    float m2 = fmaxf(sqrtf(s2), 1e-12f);

    float4 an = make_float4(a.x/m1, a.y/m1, a.z/m1, a.w/m1);
    float4 bn = make_float4(b.x/m2, b.y/m2, b.z/m2, b.w/m2);

    float dx = an.x - bn.x, dy = an.y - bn.y, dz = an.z - bn.z, dw = an.w - bn.w;
    float dp = dx*dx + dy*dy + dz*dz + dw*dw;
    #pragma unroll
    for (int off = 32; off; off >>= 1) dp += __shfl_xor(dp, off);

    // pack 4 fp8 e4m3 (OCP) and store 4B/lane (coalesced 256B/row)
    int lo = __builtin_amdgcn_cvt_pk_fp8_f32(an.x, an.y, 0,  false);
    int pk = __builtin_amdgcn_cvt_pk_fp8_f32(an.z, an.w, lo, true);
    ((int*)(z1n8 + (size_t)row * DIM))[lane] = pk;

    __shared__ float sp[4];
    if (lane == 0) {
        float sqn = s1 / (m1 * m1);                      // ||z1n||^2 (fp32-exact)
        hl[row] = 0.5f * LOG2E * sqn;
        sp[wave] = logf(expf(-dp * 0.5f) + 1e-8f) + 1.0f;  // s_pos
    }
    __syncthreads();
    if (tid == 0)
        spos_part[blockIdx.x] = sp[0] + sp[1] + sp[2] + sp[3];
}

// ---------------------------------------------------------------------------
// Kernel 2: persistent fused fp8 Z·Z^T + exp-sum, upper block-triangle.
// 512 blocks (2/CU). K=128-chunk double buffer, prefetch one chunk ahead.
// DIAGNOSTIC: whole tile loop executed twice, partial halved at the end.
// ---------------------------------------------------------------------------
__global__ __launch_bounds__(256, 2) void pair_kernel(
    const unsigned char* __restrict__ z1n8, const float* __restrict__ hl,
    float* __restrict__ negp_part) {

    __shared__ unsigned char SA[2][128 * 128];   // 32 KB
    __shared__ unsigned char SB[2][128 * 128];   // 32 KB
    __shared__ float red[4];

    const int tid = threadIdx.x, wave = tid >> 6, lane = tid & 63;
    const int bid = blockIdx.x;
    const int wr = wave >> 1, wc = wave & 1;
    const int quad = lane >> 4, colL = lane & 15;
    const int c7 = colL & 7;
    const int rl = lane >> 3, cl = lane & 7;

    auto stage = [&](int buf, int sbi, int sbj, int kc) {
        const unsigned char* gA = z1n8 + (size_t)sbi * (128 * DIM);
        const unsigned char* gB = z1n8 + (size_t)sbj * (128 * DIM);
        const size_t so = (size_t)(wave * 32 + rl) * DIM + kc * 128 + ((cl ^ rl) << 4);
        unsigned char* dA = &SA[buf][(wave * 32) * 128];
        unsigned char* dB = &SB[buf][(wave * 32) * 128];
        #pragma unroll
        for (int q = 0; q < 4; ++q) {
            GLDS16(gA + so + q * 8 * DIM, dA + q * 1024);
            GLDS16(gB + so + q * 8 * DIM, dB + q * 1024);
        }
    };

    auto compute = [&](int buf, f32x4 (&accf)[4][4]) {
        const unsigned char* A = SA[buf];
        const unsigned char* B = SB[buf];
        int8v af[4], bf[4];
        #pragma unroll
        for (int m = 0; m < 4; ++m) {
            int base = (wr * 64 + m * 16 + colL) * 128;
            union { int8v v; uint4 q[2]; } u8;
            u8.q[0] = *(const uint4*)&A[base + (((quad * 2    ) ^ c7) << 4)];
            u8.q[1] = *(const uint4*)&A[base + (((quad * 2 + 1) ^ c7) << 4)];
            af[m] = u8.v;
        }
        #pragma unroll
        for (int n = 0; n < 4; ++n) {
            int base = (wc * 64 + n * 16 + colL) * 128;
            union { int8v v; uint4 q[2]; } u8;
            u8.q[0] = *(const uint4*)&B[base + (((quad * 2    ) ^ c7) << 4)];
            u8.q[1] = *(const uint4*)&B[base + (((quad * 2 + 1) ^ c7) << 4)];
            bf[n] = u8.v;
        }
        #pragma unroll
        for (int m = 0; m < 4; ++m)
            #pragma unroll
            for (int n = 0; n < 4; ++n)
                accf[m][n] = __builtin_amdgcn_mfma_scale_f32_16x16x128_f8f6f4(
                    af[m], bf[n], accf[m][n],
                    0 /*fmtA=fp8*/, 0 /*fmtB=fp8*/,
                    0, 0x7F7F7F7F,   // scale A = 1.0 (E8M0 127)
                    0, 0x7F7F7F7F);  // scale B = 1.0
    };

    const int ntiles = (NBLK - 1 - bid) / GRID + 1;      // 4 or 5
    const int nch = ntiles * 2;                          // chunks: (tile, kc)

    float total = 0.0f;

    for (int pass = 0; pass < 2; ++pass) {               // DIAGNOSTIC 2x
        int bi, bj, nbi, nbj;
        tri_decode(bid, bi, bj);
        nbi = bi; nbj = bj;

        f32x4 accf[4][4];
        float hjn[4], hiv[4][4];

        stage(0, bi, bj, 0);                             // prologue chunk 0

        for (int ci = 0; ci < nch; ++ci) {
            const int cur = ci & 1;                      // buffer == kc
            const int kc  = ci & 1;

            __syncthreads();      // publish buf[cur] (DMA had a compute phase)

            if (ci + 1 < nch) {                          // prefetch chunk ci+1
                if (kc == 0) {
                    stage(1, bi, bj, 1);
                } else {
                    tri_decode(bid + ((ci + 1) >> 1) * GRID, nbi, nbj);
                    stage(0, nbi, nbj, 0);
                }
            }

            if (kc == 0) {
                #pragma unroll
                for (int m = 0; m < 4; ++m)
                    #pragma unroll
                    for (int n = 0; n < 4; ++n)
                        accf[m][n] = f32x4{0.f, 0.f, 0.f, 0.f};
                #pragma unroll
                for (int n = 0; n < 4; ++n)
                    hjn[n] = hl[bj * 128 + wc * 64 + n * 16 + colL];
                #pragma unroll
                for (int m = 0; m < 4; ++m)
                    #pragma unroll
                    for (int r = 0; r < 4; ++r)
                        hiv[m][r] = hl[bi * 128 + wr * 64 + m * 16 + quad * 4 + r];
            }

            compute(cur, accf);

            if (kc == 1) {
                float local = 0.0f;
                if (bi != bj) {
                    #pragma unroll
                    for (int m = 0; m < 4; ++m)
                        #pragma unroll
                        for (int reg = 0; reg < 4; ++reg)
                            #pragma unroll
                            for (int n = 0; n < 4; ++n) {
                                float arg = fminf(accf[m][n][reg] * LOG2E - hiv[m][reg] - hjn[n], 0.0f);
                                local += __builtin_amdgcn_exp2f(arg);
                            }
                    local *= 2.0f;                       // mirrored block
                } else {
                    #pragma unroll
                    for (int m = 0; m < 4; ++m)
                        #pragma unroll
                        for (int reg = 0; reg < 4; ++reg) {
                            int i = wr * 64 + m * 16 + quad * 4 + reg;
                            #pragma unroll
                            for (int n = 0; n < 4; ++n) {
                                int j = wc * 64 + n * 16 + colL;
                                float arg = fminf(accf[m][n][reg] * LOG2E - hiv[m][reg] - hjn[n], 0.0f);
                                float e = __builtin_amdgcn_exp2f(arg);
                                local += (i == j) ? 0.0f : e;
                            }
                        }
                }
                total += local;
                bi = nbi; bj = nbj;
            }
        }
    }

    total *= 0.5f;                                       // exact (pow2)

    #pragma unroll
    for (int off = 32; off; off >>= 1) total += __shfl_down(total, off);
    if (lane == 0) red[wave] = total;
    __syncthreads();
    if (tid == 0)
        negp_part[bid] = red[0] + red[1] + red[2] + red[3];
}

// ---------------------------------------------------------------------------
// Kernel 3: finalize — reduce partials in double, emit scalar.
// ---------------------------------------------------------------------------
__global__ __launch_bounds__(256) void finalize_kernel(
    const float* __restrict__ spos_part, const float* __restrict__ negp_part,
    float* __restrict__ out) {

    int tid = threadIdx.x;
    double s = 0.0, ng = 0.0;
    for (int i = tid; i < 2048; i += 256) s  += (double)spos_part[i];
    for (int i = tid; i < GRID; i += 256) ng += (double)negp_part[i];

    #pragma unroll
    for (int off = 32; off; off >>= 1) {
        s  += __shfl_xor(s,  off);
        ng += __shfl_xor(ng, off);
    }
    __shared__ double sd[4], nd[4];
    int wave = tid >> 6, lane = tid & 63;
    if (lane == 0) { sd[wave] = s; nd[wave] = ng; }
    __syncthreads();
    if (tid == 0) {
        double st = sd[0] + sd[1] + sd[2] + sd[3];
        double nt = nd[0] + nd[1] + nd[2] + nd[3];
        double mean_star = nt / (8192.0 * 8191.0) + 1e-8;
        out[0] = (float)(-st / 8192.0 + 1.5 * mean_star);
    }
}

extern "C" void kernel_launch(void* const* d_in, const int* in_sizes, int n_in,
                              void* d_out, int out_size, void* d_ws, size_t ws_size,
                              hipStream_t stream) {
    const float* z1 = (const float*)d_in[0];
    const float* z2 = (const float*)d_in[1];
    float* out = (float*)d_out;

    char* ws = (char*)d_ws;
    float* hl            = (float*)ws;                                 // 32 KB
    unsigned char* z1n8  = (unsigned char*)(ws + N_ROWS * 4);          // 2 MB fp8
    float* spos_part     = (float*)(ws + N_ROWS * 4 + N_ROWS * DIM);   // 8 KB
    float* negp_part     = spos_part + 2048;                           // 2 KB

    norm_kernel<<<N_ROWS / 4, 256, 0, stream>>>(z1, z2, z1n8, hl, spos_part);
    pair_kernel<<<GRID, 256, 0, stream>>>(z1n8, hl, negp_part);
    finalize_kernel<<<1, 256, 0, stream>>>(spos_part, negp_part, out);
}

// Round 10
// 92.142 us; speedup vs baseline: 1.1029x; 1.1029x over previous
//
#include <hip/hip_runtime.h>
#include <hip/hip_bf16.h>

// FMICLLoss: out = -mean(s_pos) + ALPHA * ( sum_{i!=j} exp(-d2_ij/2) / (N(N-1)) + EPS )
// N=8192, D=256, SIGMA=1 (inv2s2=0.5), ALPHA=1.5, EPS=1e-8, NORM_EPS=1e-12.
//
// Round 10 (R9 diagnostic: pair(1x) = 13.4us; residual is ~20us of dispatch
// boundaries at ~4us each):
//  - ||u||^2 == 1 (to 1e-7) => h_i + h_j = LOG2E is a CONSTANT. hl[] array,
//    its 20 loads/tile/lane, and the fmin clamp (arg = LOG2E*(dot-1) stays
//    in [-2,-0.9] for random data) are all removed from the pair epilogue:
//    term = exp2(fma(dot, LOG2E, -LOG2E)).
//  - d_pos = 2 - 2<u,v> => norm does ONE shuffle-reduction phase (s1,s2,s12
//    interleaved, 3-way ILP) + v_rsq, instead of two phases + sqrt + div.
//  - finalize fused into pair: 512 end-of-block release atomics (staggered;
//    R4's pathology was 2080 + 4-barrier structure), last block reduces and
//    writes out. Saves one ~4us dispatch boundary + the 1.5us kernel.
// ~47us of dur_us is harness ws re-poison + restores (untouchable).

#define N_ROWS 8192
#define DIM    256
#define LOG2E  1.4426950408889634f
#define NBLK   2080
#define GRID   512

typedef __attribute__((ext_vector_type(8))) int   int8v;
typedef __attribute__((ext_vector_type(4))) float f32x4;

#define GLDS16(gptr, lptr) \
  __builtin_amdgcn_global_load_lds((const __attribute__((address_space(1))) void*)(gptr), \
                                   (__attribute__((address_space(3))) void*)(lptr), 16, 0, 0)

__device__ inline void tri_decode(int t, int& bi, int& bj) {
    int u = NBLK - 1 - t;
    int k = (int)((sqrtf(8.0f * (float)u + 1.0f) - 1.0f) * 0.5f);
    while ((k + 1) * (k + 2) / 2 <= u) ++k;
    while (k * (k + 1) / 2 > u) --k;
    bi = 63 - k;
    bj = 63 - (u - k * (k + 1) / 2);
}

// ---------------------------------------------------------------------------
// Kernel 1: row-normalize z1 -> fp8, s_pos via Gram trick (one reduce phase).
// One wave per row (4 rows / 256-thread block). Zeroes pair's counter.
// ---------------------------------------------------------------------------
__global__ __launch_bounds__(256) void norm_kernel(
    const float* __restrict__ z1, const float* __restrict__ z2,
    unsigned char* __restrict__ z1n8, float* __restrict__ spos_part,
    unsigned* __restrict__ counter) {

    int tid  = threadIdx.x;
    int wave = tid >> 6, lane = tid & 63;
    int row  = blockIdx.x * 4 + wave;

    const float4 a = *(const float4*)(z1 + (size_t)row * DIM + lane * 4);
    const float4 b = *(const float4*)(z2 + (size_t)row * DIM + lane * 4);

    float s1  = a.x*a.x + a.y*a.y + a.z*a.z + a.w*a.w;
    float s2  = b.x*b.x + b.y*b.y + b.z*b.z + b.w*b.w;
    float s12 = a.x*b.x + a.y*b.y + a.z*b.z + a.w*b.w;
    #pragma unroll
    for (int off = 32; off; off >>= 1) {       // 3 interleaved chains (ILP)
        s1  += __shfl_xor(s1,  off);
        s2  += __shfl_xor(s2,  off);
        s12 += __shfl_xor(s12, off);
    }
    float r1 = __builtin_amdgcn_rsqf(s1);      // v_rsq_f32 (~1e-7 rel err)
    float r2 = __builtin_amdgcn_rsqf(s2);

    // pack 4 fp8 e4m3 (OCP) of a*r1; store 4B/lane (coalesced 256B/row)
    int lo = __builtin_amdgcn_cvt_pk_fp8_f32(a.x * r1, a.y * r1, 0,  false);
    int pk = __builtin_amdgcn_cvt_pk_fp8_f32(a.z * r1, a.w * r1, lo, true);
    ((int*)(z1n8 + (size_t)row * DIM))[lane] = pk;

    __shared__ float sp[4];
    if (lane == 0) {
        // d_pos = 2 - 2c, c = <u,v>  =>  s_pos = log(exp(c-1) + 1e-8) + 1
        float c = s12 * r1 * r2;
        sp[wave] = logf(__expf(c - 1.0f) + 1e-8f) + 1.0f;
    }
    __syncthreads();
    if (tid == 0)
        spos_part[blockIdx.x] = sp[0] + sp[1] + sp[2] + sp[3];
    if (blockIdx.x == 0 && tid == 0)
        *counter = 0;            // visible to pair: dispatch end = agent release
}

// ---------------------------------------------------------------------------
// Kernel 2: persistent fused fp8 Z·Z^T + exp-sum, upper block-triangle,
// with fused finalize (last of 512 blocks reduces partials, writes out).
// K=128-chunk double buffer, prefetch one chunk ahead (R8 pipeline).
// ---------------------------------------------------------------------------
__global__ __launch_bounds__(256, 2) void pair_kernel(
    const unsigned char* __restrict__ z1n8,
    const float* __restrict__ spos_part, float* __restrict__ negp_part,
    unsigned* __restrict__ counter, float* __restrict__ out) {

    __shared__ unsigned char SA[2][128 * 128];   // 32 KB
    __shared__ unsigned char SB[2][128 * 128];   // 32 KB
    __shared__ float red[4];
    __shared__ int   isLast;
    __shared__ double sd[4], nd[4];

    const int tid = threadIdx.x, wave = tid >> 6, lane = tid & 63;
    const int bid = blockIdx.x;
    const int wr = wave >> 1, wc = wave & 1;
    const int quad = lane >> 4, colL = lane & 15;
    const int c7 = colL & 7;
    const int rl = lane >> 3, cl = lane & 7;

    auto stage = [&](int buf, int sbi, int sbj, int kc) {
        const unsigned char* gA = z1n8 + (size_t)sbi * (128 * DIM);
        const unsigned char* gB = z1n8 + (size_t)sbj * (128 * DIM);
        const size_t so = (size_t)(wave * 32 + rl) * DIM + kc * 128 + ((cl ^ rl) << 4);
        unsigned char* dA = &SA[buf][(wave * 32) * 128];
        unsigned char* dB = &SB[buf][(wave * 32) * 128];
        #pragma unroll
        for (int q = 0; q < 4; ++q) {
            GLDS16(gA + so + q * 8 * DIM, dA + q * 1024);
            GLDS16(gB + so + q * 8 * DIM, dB + q * 1024);
        }
    };

    auto compute = [&](int buf, f32x4 (&accf)[4][4]) {
        const unsigned char* A = SA[buf];
        const unsigned char* B = SB[buf];
        int8v af[4], bf[4];
        #pragma unroll
        for (int m = 0; m < 4; ++m) {
            int base = (wr * 64 + m * 16 + colL) * 128;
            union { int8v v; uint4 q[2]; } u8;
            u8.q[0] = *(const uint4*)&A[base + (((quad * 2    ) ^ c7) << 4)];
            u8.q[1] = *(const uint4*)&A[base + (((quad * 2 + 1) ^ c7) << 4)];
            af[m] = u8.v;
        }
        #pragma unroll
        for (int n = 0; n < 4; ++n) {
            int base = (wc * 64 + n * 16 + colL) * 128;
            union { int8v v; uint4 q[2]; } u8;
            u8.q[0] = *(const uint4*)&B[base + (((quad * 2    ) ^ c7) << 4)];
            u8.q[1] = *(const uint4*)&B[base + (((quad * 2 + 1) ^ c7) << 4)];
            bf[n] = u8.v;
        }
        #pragma unroll
        for (int m = 0; m < 4; ++m)
            #pragma unroll
            for (int n = 0; n < 4; ++n)
                accf[m][n] = __builtin_amdgcn_mfma_scale_f32_16x16x128_f8f6f4(
                    af[m], bf[n], accf[m][n],
                    0 /*fmtA=fp8*/, 0 /*fmtB=fp8*/,
                    0, 0x7F7F7F7F,   // scale A = 1.0 (E8M0 127)
                    0, 0x7F7F7F7F);  // scale B = 1.0
    };

    const int ntiles = (NBLK - 1 - bid) / GRID + 1;      // 4 or 5
    const int nch = ntiles * 2;                          // chunks: (tile, kc)

    float total = 0.0f;
    int bi, bj, nbi, nbj;
    tri_decode(bid, bi, bj);
    nbi = bi; nbj = bj;

    f32x4 accf[4][4];

    stage(0, bi, bj, 0);                                 // prologue chunk 0

    for (int ci = 0; ci < nch; ++ci) {
        const int cur = ci & 1;                          // buffer == kc
        const int kc  = ci & 1;

        __syncthreads();          // publish buf[cur] (DMA had a compute phase)

        if (ci + 1 < nch) {                              // prefetch chunk ci+1
            if (kc == 0) {
                stage(1, bi, bj, 1);
            } else {
                tri_decode(bid + ((ci + 1) >> 1) * GRID, nbi, nbj);
                stage(0, nbi, nbj, 0);
            }
        }

        if (kc == 0) {
            #pragma unroll
            for (int m = 0; m < 4; ++m)
                #pragma unroll
                for (int n = 0; n < 4; ++n)
                    accf[m][n] = f32x4{0.f, 0.f, 0.f, 0.f};
        }

        compute(cur, accf);

        if (kc == 1) {
            // term = exp2(dot*LOG2E - LOG2E)  (h_i + h_j == LOG2E; arg is
            // always well below 0 for random data, no clamp needed)
            float local = 0.0f;
            if (bi != bj) {
                #pragma unroll
                for (int m = 0; m < 4; ++m)
                    #pragma unroll
                    for (int reg = 0; reg < 4; ++reg)
                        #pragma unroll
                        for (int n = 0; n < 4; ++n)
                            local += __builtin_amdgcn_exp2f(
                                fmaf(accf[m][n][reg], LOG2E, -LOG2E));
                local *= 2.0f;                           // mirrored block
            } else {
                #pragma unroll
                for (int m = 0; m < 4; ++m)
                    #pragma unroll
                    for (int reg = 0; reg < 4; ++reg) {
                        int i = wr * 64 + m * 16 + quad * 4 + reg;
                        #pragma unroll
                        for (int n = 0; n < 4; ++n) {
                            int j = wc * 64 + n * 16 + colL;
                            float e = __builtin_amdgcn_exp2f(
                                fmaf(accf[m][n][reg], LOG2E, -LOG2E));
                            local += (i == j) ? 0.0f : e;
                        }
                    }
            }
            total += local;
            bi = nbi; bj = nbj;
        }
    }

    // block partial
    #pragma unroll
    for (int off = 32; off; off >>= 1) total += __shfl_down(total, off);
    if (lane == 0) red[wave] = total;
    __syncthreads();

    if (tid == 0) {
        float part = red[0] + red[1] + red[2] + red[3];
        __hip_atomic_store(&negp_part[bid], part,
                           __ATOMIC_RELEASE, __HIP_MEMORY_SCOPE_AGENT);
        unsigned prev = __hip_atomic_fetch_add(counter, 1u,
                           __ATOMIC_ACQ_REL, __HIP_MEMORY_SCOPE_AGENT);
        isLast = (prev == GRID - 1) ? 1 : 0;
    }
    __syncthreads();

    if (isLast) {                            // fused finalize (last block)
        double s = 0.0, ng = 0.0;
        for (int i = tid; i < 2048; i += 256) s += (double)spos_part[i];
        for (int i = tid; i < GRID; i += 256)
            ng += (double)__hip_atomic_load(&negp_part[i],
                          __ATOMIC_RELAXED, __HIP_MEMORY_SCOPE_AGENT);
        #pragma unroll
        for (int off = 32; off; off >>= 1) {
            s  += __shfl_xor(s,  off);
            ng += __shfl_xor(ng, off);
        }
        if (lane == 0) { sd[wave] = s; nd[wave] = ng; }
        __syncthreads();
        if (tid == 0) {
            double st = sd[0] + sd[1] + sd[2] + sd[3];
            double nt = nd[0] + nd[1] + nd[2] + nd[3];
            double mean_star = nt / (8192.0 * 8191.0) + 1e-8;
            out[0] = (float)(-st / 8192.0 + 1.5 * mean_star);
        }
    }
}

extern "C" void kernel_launch(void* const* d_in, const int* in_sizes, int n_in,
                              void* d_out, int out_size, void* d_ws, size_t ws_size,
                              hipStream_t stream) {
    const float* z1 = (const float*)d_in[0];
    const float* z2 = (const float*)d_in[1];
    float* out = (float*)d_out;

    char* ws = (char*)d_ws;
    unsigned char* z1n8  = (unsigned char*)ws;                         // 2 MB fp8
    float* spos_part     = (float*)(ws + (size_t)N_ROWS * DIM);        // 8 KB
    float* negp_part     = spos_part + 2048;                           // 2 KB
    unsigned* counter    = (unsigned*)(negp_part + GRID);              // 4 B

    norm_kernel<<<N_ROWS / 4, 256, 0, stream>>>(z1, z2, z1n8, spos_part, counter);
    pair_kernel<<<GRID, 256, 0, stream>>>(z1n8, spos_part, negp_part, counter, out);
}

// Round 11
// 84.443 us; speedup vs baseline: 1.2034x; 1.0912x over previous
//
#include <hip/hip_runtime.h>
#include <hip/hip_bf16.h>

// FMICLLoss: out = -mean(s_pos) + ALPHA * ( sum_{i!=j} exp(-d2_ij/2) / (N(N-1)) + EPS )
// N=8192, D=256, SIGMA=1 (inv2s2=0.5), ALPHA=1.5, EPS=1e-8, NORM_EPS=1e-12.
//
// Round 11 = R8's zero-atomic 3-dispatch skeleton (best: 88.2us) + R10's
// algebra (both verified, absmax 0.0):
//  - norm: single 3-chain shuffle reduction (s1,s2,s12), v_rsq, Gram-trick
//    s_pos = log(exp(<u,v> - 1) + 1e-8) + 1. No hl[] array.
//  - pair epilogue: ||u||^2==1 => term = exp2(fma(dot, LOG2E, -LOG2E));
//    no hl loads, no clamp.
//  - R10's fused-finalize REVERTED: 512 same-line ACQ_REL atomics cost
//    ~+10us (serialized tail + straggler skew + L2 invalidates) — worse than
//    the ~4.5us it saved. Rule: on this part, cross-workgroup atomic
//    completion never beats a dispatch boundary.
// ~49us of dur_us is harness ws re-poison fill + input restores (untouchable).

#define N_ROWS 8192
#define DIM    256
#define LOG2E  1.4426950408889634f
#define NBLK   2080
#define GRID   512

typedef __attribute__((ext_vector_type(8))) int   int8v;
typedef __attribute__((ext_vector_type(4))) float f32x4;

#define GLDS16(gptr, lptr) \
  __builtin_amdgcn_global_load_lds((const __attribute__((address_space(1))) void*)(gptr), \
                                   (__attribute__((address_space(3))) void*)(lptr), 16, 0, 0)

__device__ inline void tri_decode(int t, int& bi, int& bj) {
    int u = NBLK - 1 - t;
    int k = (int)((sqrtf(8.0f * (float)u + 1.0f) - 1.0f) * 0.5f);
    while ((k + 1) * (k + 2) / 2 <= u) ++k;
    while (k * (k + 1) / 2 > u) --k;
    bi = 63 - k;
    bj = 63 - (u - k * (k + 1) / 2);
}

// ---------------------------------------------------------------------------
// Kernel 1: row-normalize z1 -> fp8, s_pos via Gram trick (one reduce phase).
// One wave per row (4 rows / 256-thread block). No atomics.
// ---------------------------------------------------------------------------
__global__ __launch_bounds__(256) void norm_kernel(
    const float* __restrict__ z1, const float* __restrict__ z2,
    unsigned char* __restrict__ z1n8, float* __restrict__ spos_part) {

    int tid  = threadIdx.x;
    int wave = tid >> 6, lane = tid & 63;
    int row  = blockIdx.x * 4 + wave;

    const float4 a = *(const float4*)(z1 + (size_t)row * DIM + lane * 4);
    const float4 b = *(const float4*)(z2 + (size_t)row * DIM + lane * 4);

    float s1  = a.x*a.x + a.y*a.y + a.z*a.z + a.w*a.w;
    float s2  = b.x*b.x + b.y*b.y + b.z*b.z + b.w*b.w;
    float s12 = a.x*b.x + a.y*b.y + a.z*b.z + a.w*b.w;
    #pragma unroll
    for (int off = 32; off; off >>= 1) {       // 3 interleaved chains (ILP)
        s1  += __shfl_xor(s1,  off);
        s2  += __shfl_xor(s2,  off);
        s12 += __shfl_xor(s12, off);
    }
    float r1 = __builtin_amdgcn_rsqf(s1);      // v_rsq_f32 (~1e-7 rel err)
    float r2 = __builtin_amdgcn_rsqf(s2);

    // pack 4 fp8 e4m3 (OCP) of a*r1; store 4B/lane (coalesced 256B/row)
    int lo = __builtin_amdgcn_cvt_pk_fp8_f32(a.x * r1, a.y * r1, 0,  false);
    int pk = __builtin_amdgcn_cvt_pk_fp8_f32(a.z * r1, a.w * r1, lo, true);
    ((int*)(z1n8 + (size_t)row * DIM))[lane] = pk;

    __shared__ float sp[4];
    if (lane == 0) {
        // d_pos = 2 - 2c, c = <u,v>  =>  s_pos = log(exp(c-1) + 1e-8) + 1
        float c = s12 * r1 * r2;
        sp[wave] = logf(__expf(c - 1.0f) + 1e-8f) + 1.0f;
    }
    __syncthreads();
    if (tid == 0)
        spos_part[blockIdx.x] = sp[0] + sp[1] + sp[2] + sp[3];
}

// ---------------------------------------------------------------------------
// Kernel 2: persistent fused fp8 Z·Z^T + exp-sum, upper block-triangle.
// 512 blocks (2/CU, pinned). K=128-chunk double buffer, prefetch one chunk
// ahead (each DMA has a full compute phase to land before its drain).
// One plain fp32 partial store per block. No atomics.
// ---------------------------------------------------------------------------
__global__ __launch_bounds__(256, 2) void pair_kernel(
    const unsigned char* __restrict__ z1n8, float* __restrict__ negp_part) {

    __shared__ unsigned char SA[2][128 * 128];   // 32 KB
    __shared__ unsigned char SB[2][128 * 128];   // 32 KB
    __shared__ float red[4];

    const int tid = threadIdx.x, wave = tid >> 6, lane = tid & 63;
    const int bid = blockIdx.x;
    const int wr = wave >> 1, wc = wave & 1;
    const int quad = lane >> 4, colL = lane & 15;
    const int c7 = colL & 7;
    const int rl = lane >> 3, cl = lane & 7;

    // stage one K=128 chunk (A 16KB + B 16KB), 8 GLDS16 per wave.
    // per issue: 64 lanes x 16B = 8 rows x 128B; stored 16B-block cl gets
    // logical block cl ^ rl (row&7 == rl, row groups 8-aligned) -> XOR
    // swizzle makes ds_read_b128 conflict-free with no padding.
    auto stage = [&](int buf, int sbi, int sbj, int kc) {
        const unsigned char* gA = z1n8 + (size_t)sbi * (128 * DIM);
        const unsigned char* gB = z1n8 + (size_t)sbj * (128 * DIM);
        const size_t so = (size_t)(wave * 32 + rl) * DIM + kc * 128 + ((cl ^ rl) << 4);
        unsigned char* dA = &SA[buf][(wave * 32) * 128];
        unsigned char* dB = &SB[buf][(wave * 32) * 128];
        #pragma unroll
        for (int q = 0; q < 4; ++q) {
            GLDS16(gA + so + q * 8 * DIM, dA + q * 1024);
            GLDS16(gB + so + q * 8 * DIM, dB + q * 1024);
        }
    };

    // one K=128 chunk: 16 ds_read_b128 + 16 mfma_scale per wave
    auto compute = [&](int buf, f32x4 (&accf)[4][4]) {
        const unsigned char* A = SA[buf];
        const unsigned char* B = SB[buf];
        int8v af[4], bf[4];
        #pragma unroll
        for (int m = 0; m < 4; ++m) {
            int base = (wr * 64 + m * 16 + colL) * 128;
            union { int8v v; uint4 q[2]; } u8;
            u8.q[0] = *(const uint4*)&A[base + (((quad * 2    ) ^ c7) << 4)];
            u8.q[1] = *(const uint4*)&A[base + (((quad * 2 + 1) ^ c7) << 4)];
            af[m] = u8.v;
        }
        #pragma unroll
        for (int n = 0; n < 4; ++n) {
            int base = (wc * 64 + n * 16 + colL) * 128;
            union { int8v v; uint4 q[2]; } u8;
            u8.q[0] = *(const uint4*)&B[base + (((quad * 2    ) ^ c7) << 4)];
            u8.q[1] = *(const uint4*)&B[base + (((quad * 2 + 1) ^ c7) << 4)];
            bf[n] = u8.v;
        }
        #pragma unroll
        for (int m = 0; m < 4; ++m)
            #pragma unroll
            for (int n = 0; n < 4; ++n)
                accf[m][n] = __builtin_amdgcn_mfma_scale_f32_16x16x128_f8f6f4(
                    af[m], bf[n], accf[m][n],
                    0 /*fmtA=fp8*/, 0 /*fmtB=fp8*/,
                    0, 0x7F7F7F7F,   // scale A = 1.0 (E8M0 127)
                    0, 0x7F7F7F7F);  // scale B = 1.0
    };

    const int ntiles = (NBLK - 1 - bid) / GRID + 1;      // 4 or 5
    const int nch = ntiles * 2;                          // chunks: (tile, kc)

    float total = 0.0f;
    int bi, bj, nbi, nbj;
    tri_decode(bid, bi, bj);
    nbi = bi; nbj = bj;

    f32x4 accf[4][4];

    stage(0, bi, bj, 0);                                 // prologue chunk 0

    for (int ci = 0; ci < nch; ++ci) {
        const int cur = ci & 1;                          // buffer == kc
        const int kc  = ci & 1;

        __syncthreads();          // publish buf[cur] (DMA had a compute phase)

        if (ci + 1 < nch) {                              // prefetch chunk ci+1
            if (kc == 0) {
                stage(1, bi, bj, 1);
            } else {
                tri_decode(bid + ((ci + 1) >> 1) * GRID, nbi, nbj);
                stage(0, nbi, nbj, 0);
            }
        }

        if (kc == 0) {
            #pragma unroll
            for (int m = 0; m < 4; ++m)
                #pragma unroll
                for (int n = 0; n < 4; ++n)
                    accf[m][n] = f32x4{0.f, 0.f, 0.f, 0.f};
        }

        compute(cur, accf);

        if (kc == 1) {
            // term = exp2(dot*LOG2E - LOG2E)  (h_i + h_j == LOG2E since
            // ||u||^2 == 1; arg stays well below 0 for this data, no clamp)
            float local = 0.0f;
            if (bi != bj) {
                #pragma unroll
                for (int m = 0; m < 4; ++m)
                    #pragma unroll
                    for (int reg = 0; reg < 4; ++reg)
                        #pragma unroll
                        for (int n = 0; n < 4; ++n)
                            local += __builtin_amdgcn_exp2f(
                                fmaf(accf[m][n][reg], LOG2E, -LOG2E));
                local *= 2.0f;                           // mirrored block
            } else {
                #pragma unroll
                for (int m = 0; m < 4; ++m)
                    #pragma unroll
                    for (int reg = 0; reg < 4; ++reg) {
                        int i = wr * 64 + m * 16 + quad * 4 + reg;
                        #pragma unroll
                        for (int n = 0; n < 4; ++n) {
                            int j = wc * 64 + n * 16 + colL;
                            float e = __builtin_amdgcn_exp2f(
                                fmaf(accf[m][n][reg], LOG2E, -LOG2E));
                            local += (i == j) ? 0.0f : e;
                        }
                    }
            }
            total += local;
            bi = nbi; bj = nbj;
        }
    }

    // block-level reduction, once per kernel
    #pragma unroll
    for (int off = 32; off; off >>= 1) total += __shfl_down(total, off);
    if (lane == 0) red[wave] = total;
    __syncthreads();
    if (tid == 0)
        negp_part[bid] = red[0] + red[1] + red[2] + red[3];
}

// ---------------------------------------------------------------------------
// Kernel 3: finalize — reduce partials in double, emit scalar.
// ---------------------------------------------------------------------------
__global__ __launch_bounds__(256) void finalize_kernel(
    const float* __restrict__ spos_part, const float* __restrict__ negp_part,
    float* __restrict__ out) {

    int tid = threadIdx.x;
    double s = 0.0, ng = 0.0;
    for (int i = tid; i < 2048; i += 256) s  += (double)spos_part[i];
    for (int i = tid; i < GRID; i += 256) ng += (double)negp_part[i];

    #pragma unroll
    for (int off = 32; off; off >>= 1) {
        s  += __shfl_xor(s,  off);
        ng += __shfl_xor(ng, off);
    }
    __shared__ double sd[4], nd[4];
    int wave = tid >> 6, lane = tid & 63;
    if (lane == 0) { sd[wave] = s; nd[wave] = ng; }
    __syncthreads();
    if (tid == 0) {
        double st = sd[0] + sd[1] + sd[2] + sd[3];
        double nt = nd[0] + nd[1] + nd[2] + nd[3];
        double mean_star = nt / (8192.0 * 8191.0) + 1e-8;
        out[0] = (float)(-st / 8192.0 + 1.5 * mean_star);
    }
}

extern "C" void kernel_launch(void* const* d_in, const int* in_sizes, int n_in,
                              void* d_out, int out_size, void* d_ws, size_t ws_size,
                              hipStream_t stream) {
    const float* z1 = (const float*)d_in[0];
    const float* z2 = (const float*)d_in[1];
    float* out = (float*)d_out;

    char* ws = (char*)d_ws;
    unsigned char* z1n8  = (unsigned char*)ws;                         // 2 MB fp8
    float* spos_part     = (float*)(ws + (size_t)N_ROWS * DIM);        // 8 KB
    float* negp_part     = spos_part + 2048;                           // 2 KB

    norm_kernel<<<N_ROWS / 4, 256, 0, stream>>>(z1, z2, z1n8, spos_part);
    pair_kernel<<<GRID, 256, 0, stream>>>(z1n8, negp_part);
    finalize_kernel<<<1, 256, 0, stream>>>(spos_part, negp_part, out);
}

// Round 12
// 82.829 us; speedup vs baseline: 1.2269x; 1.0195x over previous
//
#include <hip/hip_runtime.h>
#include <hip/hip_bf16.h>

// FMICLLoss: out = -mean(s_pos) + ALPHA * ( sum_{i!=j} exp(-d2_ij/2) / (N(N-1)) + EPS )
// N=8192, D=256, SIGMA=1 (inv2s2=0.5), ALPHA=1.5, EPS=1e-8, NORM_EPS=1e-12.
//
// Round 12: A-STATIONARY pair kernel. R11's pair (12.5us) was L2-staging-
// bound: 64KB/tile at ~56 B/cyc/CU needs ~2300cyc/chunk-pair vs ~1100-1500cyc
// compute phases -> every barrier exposed ~1000cyc of drain. Fix: row-major
// triangular tile order, each block owns a strip of 4-5 tiles sharing bi;
// A-panel fragments live in VGPRs (64/wave) across the strip, only B is
// staged per tile (32KB -> L2 traffic halves, fits the prefetch window) and
// LDS reads halve (af from registers). LDS = LA 32KB + LB dbuf 32KB = 64KB,
// 2 blocks/CU. Row-crossing (block-uniform, ~12% of strips) restarts the
// pipeline once (~600cyc). Norm/finalize = R11 (verified absmax 0.0).
// ~47us of dur_us is harness ws re-poison + restores (untouchable).

#define N_ROWS 8192
#define DIM    256
#define LOG2E  1.4426950408889634f
#define GRID   512

typedef __attribute__((ext_vector_type(8))) int   int8v;
typedef __attribute__((ext_vector_type(4))) float f32x4;

#define GLDS16(gptr, lptr) \
  __builtin_amdgcn_global_load_lds((const __attribute__((address_space(1))) void*)(gptr), \
                                   (__attribute__((address_space(3))) void*)(lptr), 16, 0, 0)

// ---------------------------------------------------------------------------
// Kernel 1: row-normalize z1 -> fp8, s_pos via Gram trick (one reduce phase).
// ---------------------------------------------------------------------------
__global__ __launch_bounds__(256) void norm_kernel(
    const float* __restrict__ z1, const float* __restrict__ z2,
    unsigned char* __restrict__ z1n8, float* __restrict__ spos_part) {

    int tid  = threadIdx.x;
    int wave = tid >> 6, lane = tid & 63;
    int row  = blockIdx.x * 4 + wave;

    const float4 a = *(const float4*)(z1 + (size_t)row * DIM + lane * 4);
    const float4 b = *(const float4*)(z2 + (size_t)row * DIM + lane * 4);

    float s1  = a.x*a.x + a.y*a.y + a.z*a.z + a.w*a.w;
    float s2  = b.x*b.x + b.y*b.y + b.z*b.z + b.w*b.w;
    float s12 = a.x*b.x + a.y*b.y + a.z*b.z + a.w*b.w;
    #pragma unroll
    for (int off = 32; off; off >>= 1) {       // 3 interleaved chains (ILP)
        s1  += __shfl_xor(s1,  off);
        s2  += __shfl_xor(s2,  off);
        s12 += __shfl_xor(s12, off);
    }
    float r1 = __builtin_amdgcn_rsqf(s1);
    float r2 = __builtin_amdgcn_rsqf(s2);

    int lo = __builtin_amdgcn_cvt_pk_fp8_f32(a.x * r1, a.y * r1, 0,  false);
    int pk = __builtin_amdgcn_cvt_pk_fp8_f32(a.z * r1, a.w * r1, lo, true);
    ((int*)(z1n8 + (size_t)row * DIM))[lane] = pk;

    __shared__ float sp[4];
    if (lane == 0) {
        float c = s12 * r1 * r2;               // d_pos = 2 - 2c
        sp[wave] = logf(__expf(c - 1.0f) + 1e-8f) + 1.0f;
    }
    __syncthreads();
    if (tid == 0)
        spos_part[blockIdx.x] = sp[0] + sp[1] + sp[2] + sp[3];
}

// ---------------------------------------------------------------------------
// Kernel 2: A-stationary fused fp8 Z·Z^T + exp-sum, upper block-triangle.
// Row-major strips: block b < 480 -> tiles [4b, 4b+4); else 5-tile strips.
// A-frags in VGPRs per strip; B staged per tile (K=128 dbuf, 1-chunk-ahead).
// ---------------------------------------------------------------------------
__global__ __launch_bounds__(256, 2) void pair_kernel(
    const unsigned char* __restrict__ z1n8, float* __restrict__ negp_part) {

    __shared__ unsigned char LA[2][128 * 128];   // A panel (2 K-chunks), 32 KB
    __shared__ unsigned char LB[2][128 * 128];   // B double buffer, 32 KB
    __shared__ float red[4];

    const int tid = threadIdx.x, wave = tid >> 6, lane = tid & 63;
    const int bid = blockIdx.x;
    const int wr = wave >> 1, wc = wave & 1;
    const int quad = lane >> 4, colL = lane & 15;
    const int c7 = colL & 7;
    const int rl = lane >> 3, cl = lane & 7;

    // strip [t0, t1) in row-major triangular order; cum(bi)=64bi-(bi-1)bi/2
    int t0, t1;
    if (bid < 480) { t0 = 4 * bid; t1 = t0 + 4; }
    else           { t0 = 1920 + 5 * (bid - 480); t1 = t0 + 5; }

    int bi = (int)((129.0f - sqrtf(16641.0f - 8.0f * (float)t0)) * 0.5f);
    if (bi < 0) bi = 0;
    while (64 * bi - (bi - 1) * bi / 2 > t0) --bi;
    while (64 * (bi + 1) - bi * (bi + 1) / 2 <= t0) ++bi;
    int bj = bi + (t0 - (64 * bi - (bi - 1) * bi / 2));

    // stage one 128x128B panel-chunk: per issue 64 lanes x 16B = 8 rows;
    // stored 16B-block cl receives logical block cl ^ rl (XOR swizzle) so
    // ds_read_b128 is conflict-free with no padding.
    auto stageP = [&](const unsigned char* gP, unsigned char* dst, int kc) {
        const size_t so = (size_t)(wave * 32 + rl) * DIM + kc * 128 + ((cl ^ rl) << 4);
        unsigned char* d = dst + (wave * 32) * 128;
        #pragma unroll
        for (int q = 0; q < 4; ++q)
            GLDS16(gP + so + q * 8 * DIM, d + q * 1024);
    };
    auto stageA = [&](int pbi) {
        const unsigned char* g = z1n8 + (size_t)pbi * (128 * DIM);
        stageP(g, LA[0], 0);
        stageP(g, LA[1], 1);
    };
    auto stageB = [&](int buf, int pbj, int kc) {
        stageP(z1n8 + (size_t)pbj * (128 * DIM), LB[buf], kc);
    };

    int8v af[2][4];                              // A-frags: 64 VGPRs, strip-resident
    auto readA = [&]() {
        #pragma unroll
        for (int kc = 0; kc < 2; ++kc)
            #pragma unroll
            for (int m = 0; m < 4; ++m) {
                int base = (wr * 64 + m * 16 + colL) * 128;
                union { int8v v; uint4 q[2]; } u8;
                u8.q[0] = *(const uint4*)&LA[kc][base + (((quad * 2    ) ^ c7) << 4)];
                u8.q[1] = *(const uint4*)&LA[kc][base + (((quad * 2 + 1) ^ c7) << 4)];
                af[kc][m] = u8.v;
            }
    };

    auto computeB = [&](int buf, int kc, f32x4 (&accf)[4][4]) {
        int8v bf[4];
        #pragma unroll
        for (int n = 0; n < 4; ++n) {
            int base = (wc * 64 + n * 16 + colL) * 128;
            union { int8v v; uint4 q[2]; } u8;
            u8.q[0] = *(const uint4*)&LB[buf][base + (((quad * 2    ) ^ c7) << 4)];
            u8.q[1] = *(const uint4*)&LB[buf][base + (((quad * 2 + 1) ^ c7) << 4)];
            bf[n] = u8.v;
        }
        #pragma unroll
        for (int m = 0; m < 4; ++m)
            #pragma unroll
            for (int n = 0; n < 4; ++n)
                accf[m][n] = __builtin_amdgcn_mfma_scale_f32_16x16x128_f8f6f4(
                    af[kc][m], bf[n], accf[m][n],
                    0 /*fmtA=fp8*/, 0 /*fmtB=fp8*/,
                    0, 0x7F7F7F7F,   // scale A = 1.0 (E8M0 127)
                    0, 0x7F7F7F7F);  // scale B = 1.0
    };

    float total = 0.0f;

    // strip prologue: A (both chunks) + first B chunk, one drain, A -> VGPRs
    stageA(bi);
    stageB(0, bj, 0);
    __syncthreads();
    readA();

    for (int t = t0; t < t1; ++t) {
        stageB(1, bj, 1);                        // prefetch c1 (window: compute c0)

        f32x4 accf[4][4];
        #pragma unroll
        for (int m = 0; m < 4; ++m)
            #pragma unroll
            for (int n = 0; n < 4; ++n)
                accf[m][n] = f32x4{0.f, 0.f, 0.f, 0.f};

        computeB(0, 0, accf);
        __syncthreads();                         // publish LB[1], free LB[0]

        const int  nbj      = bj + 1;
        const bool more     = (t + 1 < t1);
        const bool crossing = (nbj >= 64);       // block-uniform
        if (more && !crossing)
            stageB(0, nbj, 0);                   // prefetch next tile c0
                                                 // (window: compute c1 + epilogue)
        computeB(1, 1, accf);

        // epilogue: ||u||^2==1 -> term = exp2(fma(dot, LOG2E, -LOG2E))
        float local = 0.0f;
        if (bi != bj) {
            #pragma unroll
            for (int m = 0; m < 4; ++m)
                #pragma unroll
                for (int reg = 0; reg < 4; ++reg)
                    #pragma unroll
                    for (int n = 0; n < 4; ++n)
                        local += __builtin_amdgcn_exp2f(
                            fmaf(accf[m][n][reg], LOG2E, -LOG2E));
            local *= 2.0f;                       // mirrored block
        } else {
            #pragma unroll
            for (int m = 0; m < 4; ++m)
                #pragma unroll
                for (int reg = 0; reg < 4; ++reg) {
                    int i = wr * 64 + m * 16 + quad * 4 + reg;
                    #pragma unroll
                    for (int n = 0; n < 4; ++n) {
                        int j = wc * 64 + n * 16 + colL;
                        float e = __builtin_amdgcn_exp2f(
                            fmaf(accf[m][n][reg], LOG2E, -LOG2E));
                        local += (i == j) ? 0.0f : e;
                    }
                }
        }
        total += local;

        if (more) {
            if (crossing) {                      // new row: reload A, restart pipe
                ++bi; bj = bi;
                stageA(bi);
                stageB(0, bj, 0);
                __syncthreads();                 // drain A + B0 (LB[1] reads done)
                readA();
            } else {
                bj = nbj;
                __syncthreads();                 // publish LB[0], free LB[1]
            }
        }
    }

    // block-level reduction, once per kernel
    #pragma unroll
    for (int off = 32; off; off >>= 1) total += __shfl_down(total, off);
    if (lane == 0) red[wave] = total;
    __syncthreads();
    if (tid == 0)
        negp_part[bid] = red[0] + red[1] + red[2] + red[3];
}

// ---------------------------------------------------------------------------
// Kernel 3: finalize — reduce partials in double, emit scalar.
// ---------------------------------------------------------------------------
__global__ __launch_bounds__(256) void finalize_kernel(
    const float* __restrict__ spos_part, const float* __restrict__ negp_part,
    float* __restrict__ out) {

    int tid = threadIdx.x;
    double s = 0.0, ng = 0.0;
    for (int i = tid; i < 2048; i += 256) s  += (double)spos_part[i];
    for (int i = tid; i < GRID; i += 256) ng += (double)negp_part[i];

    #pragma unroll
    for (int off = 32; off; off >>= 1) {
        s  += __shfl_xor(s,  off);
        ng += __shfl_xor(ng, off);
    }
    __shared__ double sd[4], nd[4];
    int wave = tid >> 6, lane = tid & 63;
    if (lane == 0) { sd[wave] = s; nd[wave] = ng; }
    __syncthreads();
    if (tid == 0) {
        double st = sd[0] + sd[1] + sd[2] + sd[3];
        double nt = nd[0] + nd[1] + nd[2] + nd[3];
        double mean_star = nt / (8192.0 * 8191.0) + 1e-8;
        out[0] = (float)(-st / 8192.0 + 1.5 * mean_star);
    }
}

extern "C" void kernel_launch(void* const* d_in, const int* in_sizes, int n_in,
                              void* d_out, int out_size, void* d_ws, size_t ws_size,
                              hipStream_t stream) {
    const float* z1 = (const float*)d_in[0];
    const float* z2 = (const float*)d_in[1];
    float* out = (float*)d_out;

    char* ws = (char*)d_ws;
    unsigned char* z1n8  = (unsigned char*)ws;                         // 2 MB fp8
    float* spos_part     = (float*)(ws + (size_t)N_ROWS * DIM);        // 8 KB
    float* negp_part     = spos_part + 2048;                           // 2 KB

    norm_kernel<<<N_ROWS / 4, 256, 0, stream>>>(z1, z2, z1n8, spos_part);
    pair_kernel<<<GRID, 256, 0, stream>>>(z1n8, negp_part);
    finalize_kernel<<<1, 256, 0, stream>>>(spos_part, negp_part, out);
}